// Round 7
// baseline (769.682 us; speedup 1.0000x reference)
//
#include <hip/hip_runtime.h>
#include <math.h>
#include <cstddef>

#define B_ 16
#define T_ 256
#define D_ 128
#define H_ 128
#define L_ 4
#define G_ 512          // 4*H
#define NC_ 10
#define EPS_ 1e-5f
#define C_ 8            // pipeline chunk (timesteps per flag)
#define NCHUNK_ (T_ / C_)

typedef float f4v __attribute__((ext_vector_type(4)));

// 16 x global_load_dwordx4 -> 64 resident VGPRs (compiler cannot remat asm).
// Requires amdgpu_waves_per_eu(2,2): launch_bounds' 2nd arg is only a FLOOR on
// waves/EU; the RA still targets max occupancy and spills asm outputs
// (R4: VGPR=60, R6: VGPR=104). Pinning min=max=2 locks the pressure limit at 256.
#define LOAD_W16(w, base)                                                  \
    asm volatile(                                                          \
        "global_load_dwordx4 %0, %16, off\n\t"                            \
        "global_load_dwordx4 %1, %16, off offset:16\n\t"                  \
        "global_load_dwordx4 %2, %16, off offset:32\n\t"                  \
        "global_load_dwordx4 %3, %16, off offset:48\n\t"                  \
        "global_load_dwordx4 %4, %16, off offset:64\n\t"                  \
        "global_load_dwordx4 %5, %16, off offset:80\n\t"                  \
        "global_load_dwordx4 %6, %16, off offset:96\n\t"                  \
        "global_load_dwordx4 %7, %16, off offset:112\n\t"                 \
        "global_load_dwordx4 %8, %16, off offset:128\n\t"                 \
        "global_load_dwordx4 %9, %16, off offset:144\n\t"                 \
        "global_load_dwordx4 %10, %16, off offset:160\n\t"                \
        "global_load_dwordx4 %11, %16, off offset:176\n\t"                \
        "global_load_dwordx4 %12, %16, off offset:192\n\t"                \
        "global_load_dwordx4 %13, %16, off offset:208\n\t"                \
        "global_load_dwordx4 %14, %16, off offset:224\n\t"                \
        "global_load_dwordx4 %15, %16, off offset:240\n\t"                \
        "s_waitcnt vmcnt(0)"                                               \
        : "=&v"(w[0]), "=&v"(w[1]), "=&v"(w[2]), "=&v"(w[3]),              \
          "=&v"(w[4]), "=&v"(w[5]), "=&v"(w[6]), "=&v"(w[7]),              \
          "=&v"(w[8]), "=&v"(w[9]), "=&v"(w[10]), "=&v"(w[11]),            \
          "=&v"(w[12]), "=&v"(w[13]), "=&v"(w[14]), "=&v"(w[15])           \
        : "v"(base)                                                        \
        : "memory")

// 128-wide dot: 32 resident f4v weights vs LDS h (same-address broadcast reads)
#define DOT_LDS(dst, w, hls)                                               \
    {                                                                      \
        const f4v* h4_ = (const f4v*)(hls);                                \
        float d0 = 0.f, d1 = 0.f, d2 = 0.f, d3 = 0.f;                      \
        _Pragma("unroll")                                                  \
        for (int j_ = 0; j_ < 32; j_++) {                                  \
            f4v hv_ = h4_[j_];                                             \
            d0 = fmaf(w[j_].x, hv_.x, d0);                                 \
            d1 = fmaf(w[j_].y, hv_.y, d1);                                 \
            d2 = fmaf(w[j_].z, hv_.z, d2);                                 \
            d3 = fmaf(w[j_].w, hv_.w, d3);                                 \
        }                                                                  \
        dst = (d0 + d1) + (d2 + d3);                                       \
    }

// ---------------- device helpers ----------------
__device__ __forceinline__ float sigmoid_(float x) {
    x = fminf(fmaxf(x, -30.f), 30.f);
    return 1.f / (1.f + __expf(-x));
}
__device__ __forceinline__ float tanh_(float x) {
    float ax = fminf(fabsf(x), 15.f);
    float e = __expf(2.f * ax);
    float t = 1.f - 2.f / (e + 1.f);
    return copysignf(t, x);
}

// ---------------- stage 1: input normalize ----------------
__global__ __launch_bounds__(512) void stats_bd(const float* __restrict__ x,
                                                float* __restrict__ sum_bd,
                                                float* __restrict__ sq_bd) {
    int b = blockIdx.x;
    int tid = threadIdx.x;
    int d = tid & 127, r = tid >> 7;
    const float* xb = x + (size_t)b * T_ * D_;
    float s = 0.f, q = 0.f;
    for (int t = r; t < T_; t += 4) {
        float v = xb[t * D_ + d];
        s += v; q += v * v;
    }
    __shared__ float ls[512], lq[512];
    ls[tid] = s; lq[tid] = q;
    __syncthreads();
    if (r == 0) {
        s = ls[d] + ls[d + 128] + ls[d + 256] + ls[d + 384];
        q = lq[d] + lq[d + 128] + lq[d + 256] + lq[d + 384];
        sum_bd[b * 128 + d] = s;
        sq_bd[b * 128 + d] = q;
    }
}

__global__ __launch_bounds__(128) void stats_d(const float* __restrict__ sum_bd,
                                               const float* __restrict__ sq_bd,
                                               float* __restrict__ sdv) {
    int d = threadIdx.x;
    float s = 0.f, q = 0.f;
    for (int b = 0; b < B_; b++) { s += sum_bd[b * 128 + d]; q += sq_bd[b * 128 + d]; }
    float n = (float)(B_ * T_);
    float m = s / n;
    float varu = (q - n * m * m) / (n - 1.f);
    varu = fmaxf(varu, 0.f);
    sdv[d] = sqrtf(varu) + EPS_;
}

__global__ __launch_bounds__(256) void normalize_x(const float* __restrict__ x,
                                                   const float* __restrict__ sum_bd,
                                                   const float* __restrict__ sq_bd,
                                                   const float* __restrict__ sdv,
                                                   float* __restrict__ xn) {
    int idx = blockIdx.x * 256 + threadIdx.x;
    int d = idx & 127;
    int b = idx >> 15;
    int bd = b * 128 + d;
    float mu = sum_bd[bd] * (1.f / T_);
    float varT = sq_bd[bd] * (1.f / T_) - mu * mu;
    float s = sdv[d];
    float inv = rsqrtf(fmaxf(varT, 0.f) + EPS_ * s * s);
    xn[idx] = (x[idx] - mu) * inv;
}

// ---------------- generic K=128 GEMM ----------------
__global__ __launch_bounds__(256) void gemm_bias_k128(const float* __restrict__ A,
                                                      const float* __restrict__ Bw,
                                                      const float* __restrict__ b1,
                                                      const float* __restrict__ b2,
                                                      float* __restrict__ C, int N) {
    __shared__ __align__(16) float As[16][64];
    __shared__ __align__(16) float Bs[16][64];
    int tid = threadIdx.x;
    int m0 = blockIdx.x * 64, n0 = blockIdx.y * 64;
    int lr = tid >> 2;
    int lc = (tid & 3) << 2;
    int tm = (tid >> 4) << 2;
    int tn = (tid & 15) << 2;
    float acc[4][4] = {};
    const float* Arow = A + (size_t)(m0 + lr) * 128 + lc;
    const float* Brow = Bw + (size_t)(n0 + lr) * 128 + lc;
    for (int kb = 0; kb < 128; kb += 16) {
        float4 av = *(const float4*)(Arow + kb);
        float4 bv = *(const float4*)(Brow + kb);
        __syncthreads();
        As[lc + 0][lr] = av.x; As[lc + 1][lr] = av.y; As[lc + 2][lr] = av.z; As[lc + 3][lr] = av.w;
        Bs[lc + 0][lr] = bv.x; Bs[lc + 1][lr] = bv.y; Bs[lc + 2][lr] = bv.z; Bs[lc + 3][lr] = bv.w;
        __syncthreads();
#pragma unroll
        for (int k = 0; k < 16; k++) {
            float4 a4 = *(const float4*)&As[k][tm];
            float4 b4 = *(const float4*)&Bs[k][tn];
            float ar[4] = {a4.x, a4.y, a4.z, a4.w};
            float br[4] = {b4.x, b4.y, b4.z, b4.w};
#pragma unroll
            for (int i = 0; i < 4; i++)
#pragma unroll
                for (int j = 0; j < 4; j++)
                    acc[i][j] = fmaf(ar[i], br[j], acc[i][j]);
        }
    }
#pragma unroll
    for (int i = 0; i < 4; i++) {
        int row = m0 + tm + i;
#pragma unroll
        for (int j = 0; j < 4; j++) {
            int col = n0 + tn + j;
            float bias = b1[col] + (b2 ? b2[col] : 0.f);
            C[(size_t)row * N + col] = acc[i][j] + bias;
        }
    }
}

// ---------------- chunk-pipelined 4-layer LSTM, LDS h-broadcast ----------------
// 112 WGs x 512 thr. Thread r owns a FULL gate row: 128 weights = 32 f4v,
// asm-resident. amdgpu_waves_per_eu(2,2) locks the RA pressure limit at 256
// VGPRs (min=max=2 waves/EU) so the asm outputs cannot be spilled.
__global__ __attribute__((amdgpu_waves_per_eu(2, 2))) __launch_bounds__(512)
void scan_pipe3(const float* __restrict__ g0,      // [B][T][G] layer-0 preacts
                const float* __restrict__ Wih, const float* __restrict__ Whh,
                const float* __restrict__ bih, const float* __restrict__ bhh,
                float* __restrict__ h_glob,        // [L][B][T][H]
                float* __restrict__ ring,          // [3][B][4][C_][G]
                int* __restrict__ flag_h,          // [L][B]
                int* __restrict__ flag_g) {        // [3][B]
    const int wg = blockIdx.x;
    const int r = threadIdx.x;                     // gate row 0..511

    if (wg < 64) {
        // ======== recurrent consumer (l, b) ========
        const int l = wg >> 4, b = wg & 15;
        __shared__ __align__(16) float hsh[128];
        __shared__ float gact[512];
        f4v w[32];
        const float* wrow = Whh + ((size_t)l * G_ + r) * 128;
        LOAD_W16(w, wrow);
        { f4v* w2 = w + 16; LOAD_W16(w2, wrow + 64); }
        float c = 0.f;
        if (r < 128) hsh[r] = 0.f;
        const float* g0p = g0 + (size_t)b * T_ * G_;
        const float* rsl = (l > 0) ? ring + ((size_t)(l - 1) * 16 + b) * (4 * C_ * G_) : ring;
        float* hob = h_glob + ((size_t)l * 16 + b) * T_ * 128;
        int* fg = (l > 0) ? flag_g + (l - 1) * 16 + b : flag_g;
        int* fh = flag_h + l * 16 + b;
        float hreg[C_];
        __syncthreads();

        for (int k = 0; k < NCHUNK_; k++) {
            if (l > 0) {
                int f;
                do { f = __hip_atomic_load(fg, __ATOMIC_ACQUIRE, __HIP_MEMORY_SCOPE_AGENT); } while (f < k + 1);
            }
            // prefetch this chunk's preactivations into VGPRs
            float pre[C_];
#pragma unroll
            for (int s = 0; s < C_; s++) {
                if (l == 0) pre[s] = g0p[(size_t)(k * C_ + s) * G_ + r];
                else pre[s] = __hip_atomic_load(rsl + ((size_t)(k & 3) * C_ + s) * G_ + r,
                                                __ATOMIC_RELAXED, __HIP_MEMORY_SCOPE_AGENT);
            }
#pragma unroll
            for (int s = 0; s < C_; s++) {
                float dot;
                DOT_LDS(dot, w, hsh);
                float z = pre[s] + dot;
                float a = ((r >> 7) == 2) ? tanh_(z) : sigmoid_(z);
                gact[r] = a;
                __syncthreads();
                if (r < 128) {
                    float ai = gact[r], af = gact[128 + r], ag = gact[256 + r], ao = gact[384 + r];
                    c = fmaf(af, c, ai * ag);
                    float hn = ao * tanh_(c);
                    hsh[r] = hn;
                    hreg[s] = hn;
                }
                __syncthreads();
            }
            // chunk end: write h once (keeps vmem out of the step loop)
            if (r < 128) {
#pragma unroll
                for (int s = 0; s < C_; s++)
                    __hip_atomic_store(hob + (size_t)(k * C_ + s) * 128 + r, hreg[s],
                                       __ATOMIC_RELAXED, __HIP_MEMORY_SCOPE_AGENT);
            }
            __syncthreads();   // implicit vmcnt(0): h stores drained before publish
            if (r == 0) __hip_atomic_store(fh, k + 1, __ATOMIC_RELEASE, __HIP_MEMORY_SCOPE_AGENT);
        }
    } else {
        // ======== xproj producer (layers 1..3) ========
        const int li = (wg - 64) >> 4;     // 0..2
        const int l = li + 1, b = (wg - 64) & 15;
        __shared__ __align__(16) float hch[C_][128];
        f4v w[32];
        const float* wrow = Wih + ((size_t)l * G_ + r) * 128;
        LOAD_W16(w, wrow);
        { f4v* w2 = w + 16; LOAD_W16(w2, wrow + 64); }
        float bsum = bih[l * G_ + r] + bhh[l * G_ + r];
        const float* hsrc = h_glob + ((size_t)(l - 1) * 16 + b) * T_ * 128;
        float* rout = ring + ((size_t)li * 16 + b) * (4 * C_ * G_);
        int* fhp = flag_h + (l - 1) * 16 + b;   // upstream rec progress (data)
        int* fhme = flag_h + l * 16 + b;        // our rec progress (backpressure)
        int* fgo = flag_g + li * 16 + b;

        for (int k = 0; k < NCHUNK_; k++) {
            {
                int f;
                do { f = __hip_atomic_load(fhp, __ATOMIC_ACQUIRE, __HIP_MEMORY_SCOPE_AGENT); } while (f < k + 1);
            }
            if (k >= 4) {
                int f;
                do { f = __hip_atomic_load(fhme, __ATOMIC_ACQUIRE, __HIP_MEMORY_SCOPE_AGENT); } while (f < k - 3);
            }
            __syncthreads();   // previous chunk's hch reads complete before restage
            {   // stage 1024 floats (2 per thread)
                int i0 = r, i1 = r + 512;
                hch[i0 >> 7][i0 & 127] =
                    __hip_atomic_load(hsrc + (size_t)k * C_ * 128 + i0,
                                      __ATOMIC_RELAXED, __HIP_MEMORY_SCOPE_AGENT);
                hch[i1 >> 7][i1 & 127] =
                    __hip_atomic_load(hsrc + (size_t)k * C_ * 128 + i1,
                                      __ATOMIC_RELAXED, __HIP_MEMORY_SCOPE_AGENT);
            }
            __syncthreads();
#pragma unroll
            for (int s = 0; s < C_; s++) {
                float dot;
                DOT_LDS(dot, w, hch[s]);
                float z = dot + bsum;
                __hip_atomic_store(rout + ((size_t)(k & 3) * C_ + s) * G_ + r, z,
                                   __ATOMIC_RELAXED, __HIP_MEMORY_SCOPE_AGENT);
            }
            __syncthreads();   // drains vmcnt: ring chunk in L2 before publish
            if (r == 0) __hip_atomic_store(fgo, k + 1, __ATOMIC_RELEASE, __HIP_MEMORY_SCOPE_AGENT);
        }
    }
}

// ---------------- InstanceNorm stats ----------------
__global__ __launch_bounds__(512) void in_stats(const float* __restrict__ in,
                                                float* __restrict__ mu,
                                                float* __restrict__ inv) {
    int b = blockIdx.x;
    int tid = threadIdx.x;
    int h = tid & 127, r = tid >> 7;
    const float* ib = in + (size_t)b * T_ * H_;
    float s = 0.f, q = 0.f;
    for (int t = r; t < T_; t += 4) { float v = ib[t * H_ + h]; s += v; q += v * v; }
    __shared__ float ls[512], lq[512];
    ls[tid] = s; lq[tid] = q;
    __syncthreads();
    if (r == 0) {
        s = ls[h] + ls[h + 128] + ls[h + 256] + ls[h + 384];
        q = lq[h] + lq[h + 128] + lq[h + 256] + lq[h + 384];
        float m = s * (1.f / T_);
        float v = q * (1.f / T_) - m * m;
        mu[b * 128 + h] = m;
        inv[b * 128 + h] = rsqrtf(fmaxf(v, 0.f) + EPS_);
    }
}

__global__ __launch_bounds__(256) void apply_in(const float* __restrict__ in,
                                                const float* __restrict__ mu,
                                                const float* __restrict__ inv,
                                                float* __restrict__ out) {
    int idx = blockIdx.x * 256 + threadIdx.x;
    int h = idx & 127;
    int b = idx >> 15;
    out[idx] = (in[idx] - mu[b * 128 + h]) * inv[b * 128 + h];
}

// ---------------- attention score ----------------
__global__ __launch_bounds__(128) void score_kernel(const float* __restrict__ ph,
                                                    const float* __restrict__ px,
                                                    const float* __restrict__ mu_px,
                                                    const float* __restrict__ inv_px,
                                                    const float* __restrict__ attn_w,
                                                    float* __restrict__ lsc) {
    int bt = blockIdx.x;
    int b = bt >> 8;
    int h = threadIdx.x;
    size_t o = (size_t)bt * 128 + h;
    float v = ph[o] + (px[o] - mu_px[b * 128 + h]) * inv_px[b * 128 + h];
    float sv = tanh_(v) * attn_w[h];
    __shared__ float red[128];
    red[h] = sv;
    __syncthreads();
    for (int off = 64; off > 0; off >>= 1) {
        if (h < off) red[h] += red[h + off];
        __syncthreads();
    }
    if (h == 0) lsc[bt] = red[0];
}

__global__ __launch_bounds__(256) void softmax_t(const float* __restrict__ lsc,
                                                 float* __restrict__ wsm) {
    int b = blockIdx.x;
    int t = threadIdx.x;
    float v = lsc[b * 256 + t];
    __shared__ float red[256];
    red[t] = v; __syncthreads();
    for (int off = 128; off > 0; off >>= 1) { if (t < off) red[t] = fmaxf(red[t], red[t + off]); __syncthreads(); }
    float mx = red[0]; __syncthreads();
    float e = __expf(v - mx);
    red[t] = e; __syncthreads();
    for (int off = 128; off > 0; off >>= 1) { if (t < off) red[t] += red[t + off]; __syncthreads(); }
    wsm[b * 256 + t] = e / red[0];
}

__global__ __launch_bounds__(256) void att_map_write(const float* __restrict__ wsm,
                                                     float* __restrict__ out_att) {
    int idx = blockIdx.x * 256 + threadIdx.x;   // B*T*D
    int b = idx >> 15;
    int t = (idx >> 7) & 255;
    out_att[idx] = wsm[b * 256 + t] * (1.f / (float)D_);
}

__global__ __launch_bounds__(128) void final_kernel(const float* __restrict__ ph,
                                                    const float* __restrict__ wsm,
                                                    const float* __restrict__ fc_w,
                                                    const float* __restrict__ fc_b,
                                                    float* __restrict__ out) {
    int b = blockIdx.x;
    int h = threadIdx.x;
    const float* pb = ph + (size_t)b * T_ * H_;
    const float* wb = wsm + b * 256;
    float acc = 0.f;
    for (int t = 0; t < T_; t++) acc = fmaf(pb[t * H_ + h], wb[t], acc);
    __shared__ float ctx[128];
    ctx[h] = acc;
    __syncthreads();
    if (h < NC_) {
        float s = fc_b[h];
        const float* fw = fc_w + h * 128;
        for (int k = 0; k < 128; k++) s = fmaf(ctx[k], fw[k], s);
        out[b * NC_ + h] = s;
    }
}

// ---------------- launcher ----------------
extern "C" void kernel_launch(void* const* d_in, const int* in_sizes, int n_in,
                              void* d_out, int out_size, void* d_ws, size_t ws_size,
                              hipStream_t stream) {
    const float* x        = (const float*)d_in[0];
    const float* Wih      = (const float*)d_in[1];
    const float* Whh      = (const float*)d_in[2];
    const float* bih      = (const float*)d_in[3];
    const float* bhh      = (const float*)d_in[4];
    const float* proj_h_w = (const float*)d_in[5];
    const float* proj_h_b = (const float*)d_in[6];
    const float* proj_x_w = (const float*)d_in[7];
    const float* proj_x_b = (const float*)d_in[8];
    const float* attn_w   = (const float*)d_in[9];
    const float* fc_w     = (const float*)d_in[10];
    const float* fc_b     = (const float*)d_in[11];
    float* out = (float*)d_out;

    float* ws = (float*)d_ws;
    const size_t NTD = (size_t)B_ * T_ * D_;       // 524288
    float* xnorm  = ws;                            // NTD
    float* h_glob = xnorm + NTD;                   // 4*NTD
    float* g0     = h_glob + 4 * NTD;              // B*T*G = 4*NTD
    float* ring   = g0 + 4 * NTD;                  // 3*16*4*C_*G = 786432
    float* smalls = ring + (size_t)3 * 16 * 4 * C_ * G_;
    float* sum_bd = smalls;
    float* sq_bd  = sum_bd + 2048;
    float* sdv    = sq_bd + 2048;
    float* mu_ln  = sdv + 128;
    float* inv_ln = mu_ln + 2048;
    float* mu_px  = inv_ln + 2048;
    float* inv_px = mu_px + 2048;
    float* lsc    = inv_px + 2048;
    float* wsm    = lsc + 4096;
    int*   flags  = (int*)(wsm + 4096);
    int*   flag_h = flags;                         // [64]
    int*   flag_g = flags + 64;                    // [48]
    // post-scan reuse (dispatch-boundary ordering):
    float* lnorm = g0;                             // g0 dead after scan
    float* ph    = h_glob;                         // layer-0/1 h dead after scan
    float* px    = h_glob + NTD;
    const float* h3 = h_glob + 3 * NTD;

    hipMemsetAsync((void*)flags, 0, 128 * sizeof(int), stream);

    // input normalize
    stats_bd<<<16, 512, 0, stream>>>(x, sum_bd, sq_bd);
    stats_d<<<1, 128, 0, stream>>>(sum_bd, sq_bd, sdv);
    normalize_x<<<2048, 256, 0, stream>>>(x, sum_bd, sq_bd, sdv, xnorm);

    // layer-0 input projection (time-parallel GEMM), then chunk-pipelined stack
    dim3 g1(64, 8);
    gemm_bias_k128<<<g1, 256, 0, stream>>>(xnorm, Wih, bih, bhh, g0, G_);
    scan_pipe3<<<112, 512, 0, stream>>>(g0, Wih, Whh, bih, bhh,
                                        h_glob, ring, flag_h, flag_g);

    // post-LSTM instancenorm + projections
    in_stats<<<16, 512, 0, stream>>>(h3, mu_ln, inv_ln);
    apply_in<<<2048, 256, 0, stream>>>(h3, mu_ln, inv_ln, lnorm);
    dim3 g2(64, 2);
    gemm_bias_k128<<<g2, 256, 0, stream>>>(lnorm, proj_h_w, proj_h_b, nullptr, ph, H_);
    gemm_bias_k128<<<g2, 256, 0, stream>>>(xnorm, proj_x_w, proj_x_b, nullptr, px, H_);
    in_stats<<<16, 512, 0, stream>>>(px, mu_px, inv_px);

    // attention + classify
    score_kernel<<<4096, 128, 0, stream>>>(ph, px, mu_px, inv_px, attn_w, lsc);
    softmax_t<<<16, 256, 0, stream>>>(lsc, wsm);
    att_map_write<<<2048, 256, 0, stream>>>(wsm, out + B_ * NC_);
    final_kernel<<<16, 128, 0, stream>>>(ph, wsm, fc_w, fc_b, out);
}

// Round 9
// 678.758 us; speedup vs baseline: 1.1340x; 1.1340x over previous
//
#include <hip/hip_runtime.h>
#include <math.h>
#include <cstddef>

#define B_ 16
#define T_ 256
#define D_ 128
#define H_ 128
#define L_ 4
#define G_ 512          // 4*H
#define NC_ 10
#define EPS_ 1e-5f
#define C_ 8            // pipeline chunk (timesteps per flag)
#define NCHUNK_ (T_ / C_)

// padded LDS h layout: +4 floats per 32 -> rows of 144 floats; quarter q starts
// at q*36 floats (144B, 16B-aligned), banks 4q.. -> zero conflicts
#define HROW_ 144
#define HOFF(k) ((k) + (((k) >> 5) << 2))

typedef float f4v __attribute__((ext_vector_type(4)));

// 8 x global_load_dwordx4 -> 32 floats resident (compiler cannot remat asm)
#define LOAD_W8(w, base)                                                   \
    asm volatile(                                                          \
        "global_load_dwordx4 %0, %8, off\n\t"                             \
        "global_load_dwordx4 %1, %8, off offset:16\n\t"                   \
        "global_load_dwordx4 %2, %8, off offset:32\n\t"                   \
        "global_load_dwordx4 %3, %8, off offset:48\n\t"                   \
        "global_load_dwordx4 %4, %8, off offset:64\n\t"                   \
        "global_load_dwordx4 %5, %8, off offset:80\n\t"                   \
        "global_load_dwordx4 %6, %8, off offset:96\n\t"                   \
        "global_load_dwordx4 %7, %8, off offset:112\n\t"                  \
        "s_waitcnt vmcnt(0)"                                               \
        : "=&v"(w[0]), "=&v"(w[1]), "=&v"(w[2]), "=&v"(w[3]),              \
          "=&v"(w[4]), "=&v"(w[5]), "=&v"(w[6]), "=&v"(w[7])               \
        : "v"(base)                                                        \
        : "memory")

// 32-k partial dot: 8 resident f4v vs 8 LDS f4v at hb_ (16 lanes same addr).
// NOTE: macro params must not be named x/y/z/w (component-token substitution
// bug: DOT32(z1, w1, ..) turned `hv_.w` into `hv_.w1` in R8).
#define DOT32(dst_, warr_, hb_)                                            \
    {                                                                      \
        const f4v* h4_ = (const f4v*)(hb_);                                \
        float d0_ = 0.f, d1_ = 0.f;                                        \
        _Pragma("unroll")                                                  \
        for (int j_ = 0; j_ < 8; j_++) {                                   \
            f4v hv_ = h4_[j_];                                             \
            d0_ = fmaf(warr_[j_].x, hv_.x, d0_);                           \
            d1_ = fmaf(warr_[j_].y, hv_.y, d1_);                           \
            d0_ = fmaf(warr_[j_].z, hv_.z, d0_);                           \
            d1_ = fmaf(warr_[j_].w, hv_.w, d1_);                           \
        }                                                                  \
        dst_ = d0_ + d1_;                                                  \
    }

// ---------------- device helpers ----------------
__device__ __forceinline__ float sigmoid_(float x) {
    x = fminf(fmaxf(x, -30.f), 30.f);
    return 1.f / (1.f + __expf(-x));
}
__device__ __forceinline__ float tanh_(float x) {
    float ax = fminf(fabsf(x), 15.f);
    float e = __expf(2.f * ax);
    float t = 1.f - 2.f / (e + 1.f);
    return copysignf(t, x);
}

// ---------------- stage 1: input normalize ----------------
__global__ __launch_bounds__(512) void stats_bd(const float* __restrict__ x,
                                                float* __restrict__ sum_bd,
                                                float* __restrict__ sq_bd) {
    int b = blockIdx.x;
    int tid = threadIdx.x;
    int d = tid & 127, r = tid >> 7;
    const float* xb = x + (size_t)b * T_ * D_;
    float s = 0.f, q = 0.f;
    for (int t = r; t < T_; t += 4) {
        float v = xb[t * D_ + d];
        s += v; q += v * v;
    }
    __shared__ float ls[512], lq[512];
    ls[tid] = s; lq[tid] = q;
    __syncthreads();
    if (r == 0) {
        s = ls[d] + ls[d + 128] + ls[d + 256] + ls[d + 384];
        q = lq[d] + lq[d + 128] + lq[d + 256] + lq[d + 384];
        sum_bd[b * 128 + d] = s;
        sq_bd[b * 128 + d] = q;
    }
}

__global__ __launch_bounds__(128) void stats_d(const float* __restrict__ sum_bd,
                                               const float* __restrict__ sq_bd,
                                               float* __restrict__ sdv) {
    int d = threadIdx.x;
    float s = 0.f, q = 0.f;
    for (int b = 0; b < B_; b++) { s += sum_bd[b * 128 + d]; q += sq_bd[b * 128 + d]; }
    float n = (float)(B_ * T_);
    float m = s / n;
    float varu = (q - n * m * m) / (n - 1.f);
    varu = fmaxf(varu, 0.f);
    sdv[d] = sqrtf(varu) + EPS_;
}

__global__ __launch_bounds__(256) void normalize_x(const float* __restrict__ x,
                                                   const float* __restrict__ sum_bd,
                                                   const float* __restrict__ sq_bd,
                                                   const float* __restrict__ sdv,
                                                   float* __restrict__ xn) {
    int idx = blockIdx.x * 256 + threadIdx.x;
    int d = idx & 127;
    int b = idx >> 15;
    int bd = b * 128 + d;
    float mu = sum_bd[bd] * (1.f / T_);
    float varT = sq_bd[bd] * (1.f / T_) - mu * mu;
    float s = sdv[d];
    float inv = rsqrtf(fmaxf(varT, 0.f) + EPS_ * s * s);
    xn[idx] = (x[idx] - mu) * inv;
}

// ---------------- generic K=128 GEMM ----------------
__global__ __launch_bounds__(256) void gemm_bias_k128(const float* __restrict__ A,
                                                      const float* __restrict__ Bw,
                                                      const float* __restrict__ b1,
                                                      const float* __restrict__ b2,
                                                      float* __restrict__ C, int N) {
    __shared__ __align__(16) float As[16][64];
    __shared__ __align__(16) float Bs[16][64];
    int tid = threadIdx.x;
    int m0 = blockIdx.x * 64, n0 = blockIdx.y * 64;
    int lr = tid >> 2;
    int lc = (tid & 3) << 2;
    int tm = (tid >> 4) << 2;
    int tn = (tid & 15) << 2;
    float acc[4][4] = {};
    const float* Arow = A + (size_t)(m0 + lr) * 128 + lc;
    const float* Brow = Bw + (size_t)(n0 + lr) * 128 + lc;
    for (int kb = 0; kb < 128; kb += 16) {
        float4 av = *(const float4*)(Arow + kb);
        float4 bv = *(const float4*)(Brow + kb);
        __syncthreads();
        As[lc + 0][lr] = av.x; As[lc + 1][lr] = av.y; As[lc + 2][lr] = av.z; As[lc + 3][lr] = av.w;
        Bs[lc + 0][lr] = bv.x; Bs[lc + 1][lr] = bv.y; Bs[lc + 2][lr] = bv.z; Bs[lc + 3][lr] = bv.w;
        __syncthreads();
#pragma unroll
        for (int k = 0; k < 16; k++) {
            float4 a4 = *(const float4*)&As[k][tm];
            float4 b4 = *(const float4*)&Bs[k][tn];
            float ar[4] = {a4.x, a4.y, a4.z, a4.w};
            float br[4] = {b4.x, b4.y, b4.z, b4.w};
#pragma unroll
            for (int i = 0; i < 4; i++)
#pragma unroll
                for (int j = 0; j < 4; j++)
                    acc[i][j] = fmaf(ar[i], br[j], acc[i][j]);
        }
    }
#pragma unroll
    for (int i = 0; i < 4; i++) {
        int row = m0 + tm + i;
#pragma unroll
        for (int j = 0; j < 4; j++) {
            int col = n0 + tn + j;
            float bias = b1[col] + (b2 ? b2[col] : 0.f);
            C[(size_t)row * N + col] = acc[i][j] + bias;
        }
    }
}

// ---------------- chunk-pipelined 4-layer LSTM, quad row-sharing ----------------
// 112 WGs x 512 thr. Thread (r = tid>>2, q = tid&3) owns 4 gate rows
// (r, r+128, r+256, r+384 -- one per gate) x k-quarter q: 128 weight floats,
// asm-resident. h read per thread per step = 128 B (4x less LDS traffic than
// full-row). Quad shfl_xor(1,2) combines k-partials (bitwise-identical in all
// 4 lanes -> replicated c stays coherent, no LDS round-trip, ONE barrier/step
// via double-buffered h).
__global__ __attribute__((amdgpu_waves_per_eu(2, 2))) __launch_bounds__(512)
void scan_pipe4(const float* __restrict__ g0,      // [B][T][G] layer-0 preacts
                const float* __restrict__ Wih, const float* __restrict__ Whh,
                const float* __restrict__ bih, const float* __restrict__ bhh,
                float* __restrict__ h_glob,        // [L][B][T][H]
                float* __restrict__ ring,          // [3][B][4][C_][G]
                int* __restrict__ flag_h,          // [L][B]
                int* __restrict__ flag_g) {        // [3][B]
    const int wg = blockIdx.x;
    const int tid = threadIdx.x;
    const int r = tid >> 2, q = tid & 3;

    if (wg < 64) {
        // ======== recurrent consumer (l, b) ========
        const int l = wg >> 4, b = wg & 15;
        __shared__ __align__(16) float hsh[2][HROW_];
        f4v w0[8], w1[8], w2[8], w3[8];
        const float* wl = Whh + (size_t)l * G_ * 128;
        LOAD_W8(w0, wl + ((size_t)(0 * 128 + r)) * 128 + q * 32);
        LOAD_W8(w1, wl + ((size_t)(1 * 128 + r)) * 128 + q * 32);
        LOAD_W8(w2, wl + ((size_t)(2 * 128 + r)) * 128 + q * 32);
        LOAD_W8(w3, wl + ((size_t)(3 * 128 + r)) * 128 + q * 32);
        float c = 0.f;
        if (tid < HROW_) hsh[0][tid] = 0.f;
        const float* g0p = g0 + (size_t)b * T_ * G_;
        const float* rsl = (l > 0) ? ring + ((size_t)(l - 1) * 16 + b) * (4 * C_ * G_) : ring;
        float* hob = h_glob + ((size_t)l * 16 + b) * T_ * 128;
        int* fg = (l > 0) ? flag_g + (l - 1) * 16 + b : flag_g;
        int* fh = flag_h + l * 16 + b;
        float hreg[C_];
        __syncthreads();

        for (int k = 0; k < NCHUNK_; k++) {
            if (l > 0) {
                int f;
                do { f = __hip_atomic_load(fg, __ATOMIC_ACQUIRE, __HIP_MEMORY_SCOPE_AGENT); } while (f < k + 1);
            }
            // prefetch this chunk's preacts for the thread's 4 gate rows
            float p0[C_], p1[C_], p2[C_], p3[C_];
#pragma unroll
            for (int s = 0; s < C_; s++) {
                if (l == 0) {
                    const float* gp = g0p + (size_t)(k * C_ + s) * G_;
                    p0[s] = gp[r]; p1[s] = gp[128 + r];
                    p2[s] = gp[256 + r]; p3[s] = gp[384 + r];
                } else {
                    const float* gp = rsl + ((size_t)(k & 3) * C_ + s) * G_;
                    p0[s] = __hip_atomic_load(gp + r, __ATOMIC_RELAXED, __HIP_MEMORY_SCOPE_AGENT);
                    p1[s] = __hip_atomic_load(gp + 128 + r, __ATOMIC_RELAXED, __HIP_MEMORY_SCOPE_AGENT);
                    p2[s] = __hip_atomic_load(gp + 256 + r, __ATOMIC_RELAXED, __HIP_MEMORY_SCOPE_AGENT);
                    p3[s] = __hip_atomic_load(gp + 384 + r, __ATOMIC_RELAXED, __HIP_MEMORY_SCOPE_AGENT);
                }
            }
#pragma unroll
            for (int s = 0; s < C_; s++) {
                int t = k * C_ + s;
                const float* hb = hsh[t & 1] + q * 36;
                float zi, zf, zg, zo;
                DOT32(zi, w0, hb);
                DOT32(zf, w1, hb);
                DOT32(zg, w2, hb);
                DOT32(zo, w3, hb);
                // quad reduce (bitwise identical in all 4 lanes)
                zi += __shfl_xor(zi, 1); zi += __shfl_xor(zi, 2);
                zf += __shfl_xor(zf, 1); zf += __shfl_xor(zf, 2);
                zg += __shfl_xor(zg, 1); zg += __shfl_xor(zg, 2);
                zo += __shfl_xor(zo, 1); zo += __shfl_xor(zo, 2);
                zi += p0[s]; zf += p1[s]; zg += p2[s]; zo += p3[s];
                float ai = sigmoid_(zi), af = sigmoid_(zf);
                float ag = tanh_(zg),    ao = sigmoid_(zo);
                c = fmaf(af, c, ai * ag);
                float hn = ao * tanh_(c);
                if (q == 0) hsh[(t + 1) & 1][HOFF(r)] = hn;
                hreg[s] = hn;
                __syncthreads();
            }
            // chunk end: write h once (keeps vmem out of the step loop)
            if (q == 0) {
#pragma unroll
                for (int s = 0; s < C_; s++)
                    __hip_atomic_store(hob + (size_t)(k * C_ + s) * 128 + r, hreg[s],
                                       __ATOMIC_RELAXED, __HIP_MEMORY_SCOPE_AGENT);
            }
            __syncthreads();   // implicit vmcnt(0): h stores drained before publish
            if (tid == 0) __hip_atomic_store(fh, k + 1, __ATOMIC_RELEASE, __HIP_MEMORY_SCOPE_AGENT);
        }
    } else {
        // ======== xproj producer (layers 1..3) ========
        const int li = (wg - 64) >> 4;     // 0..2
        const int l = li + 1, b = (wg - 64) & 15;
        __shared__ __align__(16) float hch[C_][HROW_];
        f4v w0[8], w1[8], w2[8], w3[8];
        const float* wl = Wih + (size_t)l * G_ * 128;
        LOAD_W8(w0, wl + ((size_t)(0 * 128 + r)) * 128 + q * 32);
        LOAD_W8(w1, wl + ((size_t)(1 * 128 + r)) * 128 + q * 32);
        LOAD_W8(w2, wl + ((size_t)(2 * 128 + r)) * 128 + q * 32);
        LOAD_W8(w3, wl + ((size_t)(3 * 128 + r)) * 128 + q * 32);
        float bs0 = bih[l * G_ + r] + bhh[l * G_ + r];
        float bs1 = bih[l * G_ + 128 + r] + bhh[l * G_ + 128 + r];
        float bs2 = bih[l * G_ + 256 + r] + bhh[l * G_ + 256 + r];
        float bs3 = bih[l * G_ + 384 + r] + bhh[l * G_ + 384 + r];
        const float* hsrc = h_glob + ((size_t)(l - 1) * 16 + b) * T_ * 128;
        float* rout = ring + ((size_t)li * 16 + b) * (4 * C_ * G_);
        int* fhp = flag_h + (l - 1) * 16 + b;   // upstream rec progress (data)
        int* fhme = flag_h + l * 16 + b;        // our rec progress (backpressure)
        int* fgo = flag_g + li * 16 + b;

        for (int k = 0; k < NCHUNK_; k++) {
            {
                int f;
                do { f = __hip_atomic_load(fhp, __ATOMIC_ACQUIRE, __HIP_MEMORY_SCOPE_AGENT); } while (f < k + 1);
            }
            if (k >= 4) {
                int f;
                do { f = __hip_atomic_load(fhme, __ATOMIC_ACQUIRE, __HIP_MEMORY_SCOPE_AGENT); } while (f < k - 3);
            }
            __syncthreads();   // previous chunk's hch reads complete before restage
            {   // stage 1024 h values (2 per thread) into padded layout
                int i0 = tid, i1 = tid + 512;
                hch[i0 >> 7][HOFF(i0 & 127)] =
                    __hip_atomic_load(hsrc + (size_t)k * C_ * 128 + i0,
                                      __ATOMIC_RELAXED, __HIP_MEMORY_SCOPE_AGENT);
                hch[i1 >> 7][HOFF(i1 & 127)] =
                    __hip_atomic_load(hsrc + (size_t)k * C_ * 128 + i1,
                                      __ATOMIC_RELAXED, __HIP_MEMORY_SCOPE_AGENT);
            }
            __syncthreads();
#pragma unroll
            for (int s = 0; s < C_; s++) {
                const float* hb = hch[s] + q * 36;
                float z0, z1, z2, z3;
                DOT32(z0, w0, hb);
                DOT32(z1, w1, hb);
                DOT32(z2, w2, hb);
                DOT32(z3, w3, hb);
                z0 += __shfl_xor(z0, 1); z0 += __shfl_xor(z0, 2);
                z1 += __shfl_xor(z1, 1); z1 += __shfl_xor(z1, 2);
                z2 += __shfl_xor(z2, 1); z2 += __shfl_xor(z2, 2);
                z3 += __shfl_xor(z3, 1); z3 += __shfl_xor(z3, 2);
                if (q == 0) {
                    float* ro = rout + ((size_t)(k & 3) * C_ + s) * G_;
                    __hip_atomic_store(ro + r, z0 + bs0, __ATOMIC_RELAXED, __HIP_MEMORY_SCOPE_AGENT);
                    __hip_atomic_store(ro + 128 + r, z1 + bs1, __ATOMIC_RELAXED, __HIP_MEMORY_SCOPE_AGENT);
                    __hip_atomic_store(ro + 256 + r, z2 + bs2, __ATOMIC_RELAXED, __HIP_MEMORY_SCOPE_AGENT);
                    __hip_atomic_store(ro + 384 + r, z3 + bs3, __ATOMIC_RELAXED, __HIP_MEMORY_SCOPE_AGENT);
                }
            }
            __syncthreads();   // drains vmcnt: ring chunk in L2 before publish
            if (tid == 0) __hip_atomic_store(fgo, k + 1, __ATOMIC_RELEASE, __HIP_MEMORY_SCOPE_AGENT);
        }
    }
}

// ---------------- InstanceNorm stats ----------------
__global__ __launch_bounds__(512) void in_stats(const float* __restrict__ in,
                                                float* __restrict__ mu,
                                                float* __restrict__ inv) {
    int b = blockIdx.x;
    int tid = threadIdx.x;
    int h = tid & 127, r = tid >> 7;
    const float* ib = in + (size_t)b * T_ * H_;
    float s = 0.f, q = 0.f;
    for (int t = r; t < T_; t += 4) { float v = ib[t * H_ + h]; s += v; q += v * v; }
    __shared__ float ls[512], lq[512];
    ls[tid] = s; lq[tid] = q;
    __syncthreads();
    if (r == 0) {
        s = ls[h] + ls[h + 128] + ls[h + 256] + ls[h + 384];
        q = lq[h] + lq[h + 128] + lq[h + 256] + lq[h + 384];
        float m = s * (1.f / T_);
        float v = q * (1.f / T_) - m * m;
        mu[b * 128 + h] = m;
        inv[b * 128 + h] = rsqrtf(fmaxf(v, 0.f) + EPS_);
    }
}

__global__ __launch_bounds__(256) void apply_in(const float* __restrict__ in,
                                                const float* __restrict__ mu,
                                                const float* __restrict__ inv,
                                                float* __restrict__ out) {
    int idx = blockIdx.x * 256 + threadIdx.x;
    int h = idx & 127;
    int b = idx >> 15;
    out[idx] = (in[idx] - mu[b * 128 + h]) * inv[b * 128 + h];
}

// ---------------- attention score ----------------
__global__ __launch_bounds__(128) void score_kernel(const float* __restrict__ ph,
                                                    const float* __restrict__ px,
                                                    const float* __restrict__ mu_px,
                                                    const float* __restrict__ inv_px,
                                                    const float* __restrict__ attn_w,
                                                    float* __restrict__ lsc) {
    int bt = blockIdx.x;
    int b = bt >> 8;
    int h = threadIdx.x;
    size_t o = (size_t)bt * 128 + h;
    float v = ph[o] + (px[o] - mu_px[b * 128 + h]) * inv_px[b * 128 + h];
    float sv = tanh_(v) * attn_w[h];
    __shared__ float red[128];
    red[h] = sv;
    __syncthreads();
    for (int off = 64; off > 0; off >>= 1) {
        if (h < off) red[h] += red[h + off];
        __syncthreads();
    }
    if (h == 0) lsc[bt] = red[0];
}

__global__ __launch_bounds__(256) void softmax_t(const float* __restrict__ lsc,
                                                 float* __restrict__ wsm) {
    int b = blockIdx.x;
    int t = threadIdx.x;
    float v = lsc[b * 256 + t];
    __shared__ float red[256];
    red[t] = v; __syncthreads();
    for (int off = 128; off > 0; off >>= 1) { if (t < off) red[t] = fmaxf(red[t], red[t + off]); __syncthreads(); }
    float mx = red[0]; __syncthreads();
    float e = __expf(v - mx);
    red[t] = e; __syncthreads();
    for (int off = 128; off > 0; off >>= 1) { if (t < off) red[t] += red[t + off]; __syncthreads(); }
    wsm[b * 256 + t] = e / red[0];
}

__global__ __launch_bounds__(256) void att_map_write(const float* __restrict__ wsm,
                                                     float* __restrict__ out_att) {
    int idx = blockIdx.x * 256 + threadIdx.x;   // B*T*D
    int b = idx >> 15;
    int t = (idx >> 7) & 255;
    out_att[idx] = wsm[b * 256 + t] * (1.f / (float)D_);
}

__global__ __launch_bounds__(128) void final_kernel(const float* __restrict__ ph,
                                                    const float* __restrict__ wsm,
                                                    const float* __restrict__ fc_w,
                                                    const float* __restrict__ fc_b,
                                                    float* __restrict__ out) {
    int b = blockIdx.x;
    int h = threadIdx.x;
    const float* pb = ph + (size_t)b * T_ * H_;
    const float* wb = wsm + b * 256;
    float acc = 0.f;
    for (int t = 0; t < T_; t++) acc = fmaf(pb[t * H_ + h], wb[t], acc);
    __shared__ float ctx[128];
    ctx[h] = acc;
    __syncthreads();
    if (h < NC_) {
        float s = fc_b[h];
        const float* fw = fc_w + h * 128;
        for (int k = 0; k < 128; k++) s = fmaf(ctx[k], fw[k], s);
        out[b * NC_ + h] = s;
    }
}

// ---------------- launcher ----------------
extern "C" void kernel_launch(void* const* d_in, const int* in_sizes, int n_in,
                              void* d_out, int out_size, void* d_ws, size_t ws_size,
                              hipStream_t stream) {
    const float* x        = (const float*)d_in[0];
    const float* Wih      = (const float*)d_in[1];
    const float* Whh      = (const float*)d_in[2];
    const float* bih      = (const float*)d_in[3];
    const float* bhh      = (const float*)d_in[4];
    const float* proj_h_w = (const float*)d_in[5];
    const float* proj_h_b = (const float*)d_in[6];
    const float* proj_x_w = (const float*)d_in[7];
    const float* proj_x_b = (const float*)d_in[8];
    const float* attn_w   = (const float*)d_in[9];
    const float* fc_w     = (const float*)d_in[10];
    const float* fc_b     = (const float*)d_in[11];
    float* out = (float*)d_out;

    float* ws = (float*)d_ws;
    const size_t NTD = (size_t)B_ * T_ * D_;       // 524288
    float* xnorm  = ws;                            // NTD
    float* h_glob = xnorm + NTD;                   // 4*NTD
    float* g0     = h_glob + 4 * NTD;              // B*T*G = 4*NTD
    float* ring   = g0 + 4 * NTD;                  // 3*16*4*C_*G = 786432
    float* smalls = ring + (size_t)3 * 16 * 4 * C_ * G_;
    float* sum_bd = smalls;
    float* sq_bd  = sum_bd + 2048;
    float* sdv    = sq_bd + 2048;
    float* mu_ln  = sdv + 128;
    float* inv_ln = mu_ln + 2048;
    float* mu_px  = inv_ln + 2048;
    float* inv_px = mu_px + 2048;
    float* lsc    = inv_px + 2048;
    float* wsm    = lsc + 4096;
    int*   flags  = (int*)(wsm + 4096);
    int*   flag_h = flags;                         // [64]
    int*   flag_g = flags + 64;                    // [48]
    // post-scan reuse (dispatch-boundary ordering):
    float* lnorm = g0;                             // g0 dead after scan
    float* ph    = h_glob;                         // layer-0/1 h dead after scan
    float* px    = h_glob + NTD;
    const float* h3 = h_glob + 3 * NTD;

    hipMemsetAsync((void*)flags, 0, 128 * sizeof(int), stream);

    // input normalize
    stats_bd<<<16, 512, 0, stream>>>(x, sum_bd, sq_bd);
    stats_d<<<1, 128, 0, stream>>>(sum_bd, sq_bd, sdv);
    normalize_x<<<2048, 256, 0, stream>>>(x, sum_bd, sq_bd, sdv, xnorm);

    // layer-0 input projection (time-parallel GEMM), then chunk-pipelined stack
    dim3 g1(64, 8);
    gemm_bias_k128<<<g1, 256, 0, stream>>>(xnorm, Wih, bih, bhh, g0, G_);
    scan_pipe4<<<112, 512, 0, stream>>>(g0, Wih, Whh, bih, bhh,
                                        h_glob, ring, flag_h, flag_g);

    // post-LSTM instancenorm + projections
    in_stats<<<16, 512, 0, stream>>>(h3, mu_ln, inv_ln);
    apply_in<<<2048, 256, 0, stream>>>(h3, mu_ln, inv_ln, lnorm);
    dim3 g2(64, 2);
    gemm_bias_k128<<<g2, 256, 0, stream>>>(lnorm, proj_h_w, proj_h_b, nullptr, ph, H_);
    gemm_bias_k128<<<g2, 256, 0, stream>>>(xnorm, proj_x_w, proj_x_b, nullptr, px, H_);
    in_stats<<<16, 512, 0, stream>>>(px, mu_px, inv_px);

    // attention + classify
    score_kernel<<<4096, 128, 0, stream>>>(ph, px, mu_px, inv_px, attn_w, lsc);
    softmax_t<<<16, 256, 0, stream>>>(lsc, wsm);
    att_map_write<<<2048, 256, 0, stream>>>(wsm, out + B_ * NC_);
    final_kernel<<<16, 128, 0, stream>>>(ph, wsm, fc_w, fc_b, out);
}

// Round 10
// 520.580 us; speedup vs baseline: 1.4785x; 1.3038x over previous
//
#include <hip/hip_runtime.h>
#include <math.h>
#include <cstddef>

#define B_ 16
#define T_ 256
#define D_ 128
#define H_ 128
#define L_ 4
#define G_ 512          // 4*H
#define NC_ 10
#define EPS_ 1e-5f
#define C_ 16           // pipeline chunk (timesteps per flag)
#define NCHUNK_ (T_ / C_)

// padded LDS h layout: +4 floats per 32 -> rows of 144 floats; quarter q starts
// at q*36 floats (144B, 16B-aligned) -> zero conflicts
#define HROW_ 144
#define HOFF(k) ((k) + (((k) >> 5) << 2))

typedef float f4v __attribute__((ext_vector_type(4)));

// 8 x global_load_dwordx4 -> 32 floats resident (compiler cannot remat asm)
#define LOAD_W8(w, base)                                                   \
    asm volatile(                                                          \
        "global_load_dwordx4 %0, %8, off\n\t"                             \
        "global_load_dwordx4 %1, %8, off offset:16\n\t"                   \
        "global_load_dwordx4 %2, %8, off offset:32\n\t"                   \
        "global_load_dwordx4 %3, %8, off offset:48\n\t"                   \
        "global_load_dwordx4 %4, %8, off offset:64\n\t"                   \
        "global_load_dwordx4 %5, %8, off offset:80\n\t"                   \
        "global_load_dwordx4 %6, %8, off offset:96\n\t"                   \
        "global_load_dwordx4 %7, %8, off offset:112\n\t"                  \
        "s_waitcnt vmcnt(0)"                                               \
        : "=&v"(w[0]), "=&v"(w[1]), "=&v"(w[2]), "=&v"(w[3]),              \
          "=&v"(w[4]), "=&v"(w[5]), "=&v"(w[6]), "=&v"(w[7])               \
        : "v"(base)                                                        \
        : "memory")

// 32-k partial dot (macro params must not collide with x/y/z/w tokens)
#define DOT32(dst_, warr_, hb_)                                            \
    {                                                                      \
        const f4v* h4_ = (const f4v*)(hb_);                                \
        float d0_ = 0.f, d1_ = 0.f;                                        \
        _Pragma("unroll")                                                  \
        for (int j_ = 0; j_ < 8; j_++) {                                   \
            f4v hv_ = h4_[j_];                                             \
            d0_ = fmaf(warr_[j_].x, hv_.x, d0_);                           \
            d1_ = fmaf(warr_[j_].y, hv_.y, d1_);                           \
            d0_ = fmaf(warr_[j_].z, hv_.z, d0_);                           \
            d1_ = fmaf(warr_[j_].w, hv_.w, d1_);                           \
        }                                                                  \
        dst_ = d0_ + d1_;                                                  \
    }

// ---------------- device helpers ----------------
__device__ __forceinline__ float sigmoid_(float x) {
    x = fminf(fmaxf(x, -30.f), 30.f);
    return 1.f / (1.f + __expf(-x));
}
__device__ __forceinline__ float tanh_(float x) {
    float ax = fminf(fabsf(x), 15.f);
    float e = __expf(2.f * ax);
    float t = 1.f - 2.f / (e + 1.f);
    return copysignf(t, x);
}
// single-thread spin: RELAXED polls + s_sleep, one final ACQUIRE for ordering
__device__ __forceinline__ void wait_ge_(int* p, int v) {
    if (__hip_atomic_load(p, __ATOMIC_RELAXED, __HIP_MEMORY_SCOPE_AGENT) < v) {
        do { __builtin_amdgcn_s_sleep(1); }
        while (__hip_atomic_load(p, __ATOMIC_RELAXED, __HIP_MEMORY_SCOPE_AGENT) < v);
    }
    (void)__hip_atomic_load(p, __ATOMIC_ACQUIRE, __HIP_MEMORY_SCOPE_AGENT);
}

// ---------------- stage 1: input normalize ----------------
__global__ __launch_bounds__(512) void stats_bd(const float* __restrict__ x,
                                                float* __restrict__ sum_bd,
                                                float* __restrict__ sq_bd) {
    int b = blockIdx.x;
    int tid = threadIdx.x;
    int d = tid & 127, r = tid >> 7;
    const float* xb = x + (size_t)b * T_ * D_;
    float s = 0.f, q = 0.f;
    for (int t = r; t < T_; t += 4) {
        float v = xb[t * D_ + d];
        s += v; q += v * v;
    }
    __shared__ float ls[512], lq[512];
    ls[tid] = s; lq[tid] = q;
    __syncthreads();
    if (r == 0) {
        s = ls[d] + ls[d + 128] + ls[d + 256] + ls[d + 384];
        q = lq[d] + lq[d + 128] + lq[d + 256] + lq[d + 384];
        sum_bd[b * 128 + d] = s;
        sq_bd[b * 128 + d] = q;
    }
}

__global__ __launch_bounds__(128) void stats_d(const float* __restrict__ sum_bd,
                                               const float* __restrict__ sq_bd,
                                               float* __restrict__ sdv) {
    int d = threadIdx.x;
    float s = 0.f, q = 0.f;
    for (int b = 0; b < B_; b++) { s += sum_bd[b * 128 + d]; q += sq_bd[b * 128 + d]; }
    float n = (float)(B_ * T_);
    float m = s / n;
    float varu = (q - n * m * m) / (n - 1.f);
    varu = fmaxf(varu, 0.f);
    sdv[d] = sqrtf(varu) + EPS_;
}

__global__ __launch_bounds__(256) void normalize_x(const float* __restrict__ x,
                                                   const float* __restrict__ sum_bd,
                                                   const float* __restrict__ sq_bd,
                                                   const float* __restrict__ sdv,
                                                   float* __restrict__ xn) {
    int idx = blockIdx.x * 256 + threadIdx.x;
    int d = idx & 127;
    int b = idx >> 15;
    int bd = b * 128 + d;
    float mu = sum_bd[bd] * (1.f / T_);
    float varT = sq_bd[bd] * (1.f / T_) - mu * mu;
    float s = sdv[d];
    float inv = rsqrtf(fmaxf(varT, 0.f) + EPS_ * s * s);
    xn[idx] = (x[idx] - mu) * inv;
}

// ---------------- generic K=128 GEMM ----------------
__global__ __launch_bounds__(256) void gemm_bias_k128(const float* __restrict__ A,
                                                      const float* __restrict__ Bw,
                                                      const float* __restrict__ b1,
                                                      const float* __restrict__ b2,
                                                      float* __restrict__ C, int N) {
    __shared__ __align__(16) float As[16][64];
    __shared__ __align__(16) float Bs[16][64];
    int tid = threadIdx.x;
    int m0 = blockIdx.x * 64, n0 = blockIdx.y * 64;
    int lr = tid >> 2;
    int lc = (tid & 3) << 2;
    int tm = (tid >> 4) << 2;
    int tn = (tid & 15) << 2;
    float acc[4][4] = {};
    const float* Arow = A + (size_t)(m0 + lr) * 128 + lc;
    const float* Brow = Bw + (size_t)(n0 + lr) * 128 + lc;
    for (int kb = 0; kb < 128; kb += 16) {
        float4 av = *(const float4*)(Arow + kb);
        float4 bv = *(const float4*)(Brow + kb);
        __syncthreads();
        As[lc + 0][lr] = av.x; As[lc + 1][lr] = av.y; As[lc + 2][lr] = av.z; As[lc + 3][lr] = av.w;
        Bs[lc + 0][lr] = bv.x; Bs[lc + 1][lr] = bv.y; Bs[lc + 2][lr] = bv.z; Bs[lc + 3][lr] = bv.w;
        __syncthreads();
#pragma unroll
        for (int k = 0; k < 16; k++) {
            float4 a4 = *(const float4*)&As[k][tm];
            float4 b4 = *(const float4*)&Bs[k][tn];
            float ar[4] = {a4.x, a4.y, a4.z, a4.w};
            float br[4] = {b4.x, b4.y, b4.z, b4.w};
#pragma unroll
            for (int i = 0; i < 4; i++)
#pragma unroll
                for (int j = 0; j < 4; j++)
                    acc[i][j] = fmaf(ar[i], br[j], acc[i][j]);
        }
    }
#pragma unroll
    for (int i = 0; i < 4; i++) {
        int row = m0 + tm + i;
#pragma unroll
        for (int j = 0; j < 4; j++) {
            int col = n0 + tn + j;
            float bias = b1[col] + (b2 ? b2[col] : 0.f);
            C[(size_t)row * N + col] = acc[i][j] + bias;
        }
    }
}

// ---------------- chunk-pipelined 4-layer LSTM, quad row-sharing, C_=16 ----------------
__global__ __attribute__((amdgpu_waves_per_eu(2, 2))) __launch_bounds__(512)
void scan_pipe4(const float* __restrict__ g0,      // [B][T][G] layer-0 preacts
                const float* __restrict__ Wih, const float* __restrict__ Whh,
                const float* __restrict__ bih, const float* __restrict__ bhh,
                float* __restrict__ h_glob,        // [L][B][T][H]
                float* __restrict__ ring,          // [3][B][4][C_][G]
                int* __restrict__ flag_h,          // [L][B]
                int* __restrict__ flag_g) {        // [3][B]
    const int wg = blockIdx.x;
    const int tid = threadIdx.x;
    const int r = tid >> 2, q = tid & 3;

    if (wg < 64) {
        // ======== recurrent consumer (l, b) ========
        const int l = wg >> 4, b = wg & 15;
        __shared__ __align__(16) float hsh[2][HROW_];
        f4v w0[8], w1[8], w2[8], w3[8];
        const float* wl = Whh + (size_t)l * G_ * 128;
        LOAD_W8(w0, wl + ((size_t)(0 * 128 + r)) * 128 + q * 32);
        LOAD_W8(w1, wl + ((size_t)(1 * 128 + r)) * 128 + q * 32);
        LOAD_W8(w2, wl + ((size_t)(2 * 128 + r)) * 128 + q * 32);
        LOAD_W8(w3, wl + ((size_t)(3 * 128 + r)) * 128 + q * 32);
        float c = 0.f;
        if (tid < HROW_) hsh[0][tid] = 0.f;
        const float* g0p = g0 + (size_t)b * T_ * G_;
        const float* rsl = (l > 0) ? ring + ((size_t)(l - 1) * 16 + b) * (4 * C_ * G_) : ring;
        float* hob = h_glob + ((size_t)l * 16 + b) * T_ * 128;
        int* fg = (l > 0) ? flag_g + (l - 1) * 16 + b : flag_g;
        int* fh = flag_h + l * 16 + b;
        float hreg[C_];
        __syncthreads();

        for (int k = 0; k < NCHUNK_; k++) {
            if (l > 0) {
                if (tid == 0) wait_ge_(fg, k + 1);
                __syncthreads();
            }
#pragma unroll
            for (int half = 0; half < 2; half++) {
                // prefetch 8 steps of preacts for this thread's 4 gate rows
                float p0[8], p1[8], p2[8], p3[8];
#pragma unroll
                for (int s8 = 0; s8 < 8; s8++) {
                    int s = half * 8 + s8;
                    if (l == 0) {
                        const float* gp = g0p + (size_t)(k * C_ + s) * G_;
                        p0[s8] = gp[r]; p1[s8] = gp[128 + r];
                        p2[s8] = gp[256 + r]; p3[s8] = gp[384 + r];
                    } else {
                        const float* gp = rsl + ((size_t)(k & 3) * C_ + s) * G_;
                        p0[s8] = __hip_atomic_load(gp + r, __ATOMIC_RELAXED, __HIP_MEMORY_SCOPE_AGENT);
                        p1[s8] = __hip_atomic_load(gp + 128 + r, __ATOMIC_RELAXED, __HIP_MEMORY_SCOPE_AGENT);
                        p2[s8] = __hip_atomic_load(gp + 256 + r, __ATOMIC_RELAXED, __HIP_MEMORY_SCOPE_AGENT);
                        p3[s8] = __hip_atomic_load(gp + 384 + r, __ATOMIC_RELAXED, __HIP_MEMORY_SCOPE_AGENT);
                    }
                }
#pragma unroll
                for (int s8 = 0; s8 < 8; s8++) {
                    int s = half * 8 + s8;
                    int t = k * C_ + s;
                    const float* hb = hsh[t & 1] + q * 36;
                    float zi, zf, zg, zo;
                    DOT32(zi, w0, hb);
                    DOT32(zf, w1, hb);
                    DOT32(zg, w2, hb);
                    DOT32(zo, w3, hb);
                    zi += __shfl_xor(zi, 1); zi += __shfl_xor(zi, 2);
                    zf += __shfl_xor(zf, 1); zf += __shfl_xor(zf, 2);
                    zg += __shfl_xor(zg, 1); zg += __shfl_xor(zg, 2);
                    zo += __shfl_xor(zo, 1); zo += __shfl_xor(zo, 2);
                    zi += p0[s8]; zf += p1[s8]; zg += p2[s8]; zo += p3[s8];
                    float ai = sigmoid_(zi), af = sigmoid_(zf);
                    float ag = tanh_(zg),    ao = sigmoid_(zo);
                    c = fmaf(af, c, ai * ag);
                    float hn = ao * tanh_(c);
                    if (q == 0) hsh[(t + 1) & 1][HOFF(r)] = hn;
                    hreg[s] = hn;
                    __syncthreads();
                }
            }
            // chunk end: write h once (keeps vmem out of the step loop)
            if (q == 0) {
#pragma unroll
                for (int s = 0; s < C_; s++)
                    __hip_atomic_store(hob + (size_t)(k * C_ + s) * 128 + r, hreg[s],
                                       __ATOMIC_RELAXED, __HIP_MEMORY_SCOPE_AGENT);
            }
            __syncthreads();   // implicit vmcnt(0): h stores drained before publish
            if (tid == 0) __hip_atomic_store(fh, k + 1, __ATOMIC_RELEASE, __HIP_MEMORY_SCOPE_AGENT);
        }
    } else {
        // ======== xproj producer (layers 1..3) ========
        const int li = (wg - 64) >> 4;     // 0..2
        const int l = li + 1, b = (wg - 64) & 15;
        __shared__ __align__(16) float hch[C_][HROW_];
        f4v w0[8], w1[8], w2[8], w3[8];
        const float* wl = Wih + (size_t)l * G_ * 128;
        LOAD_W8(w0, wl + ((size_t)(0 * 128 + r)) * 128 + q * 32);
        LOAD_W8(w1, wl + ((size_t)(1 * 128 + r)) * 128 + q * 32);
        LOAD_W8(w2, wl + ((size_t)(2 * 128 + r)) * 128 + q * 32);
        LOAD_W8(w3, wl + ((size_t)(3 * 128 + r)) * 128 + q * 32);
        float bs0 = bih[l * G_ + r] + bhh[l * G_ + r];
        float bs1 = bih[l * G_ + 128 + r] + bhh[l * G_ + 128 + r];
        float bs2 = bih[l * G_ + 256 + r] + bhh[l * G_ + 256 + r];
        float bs3 = bih[l * G_ + 384 + r] + bhh[l * G_ + 384 + r];
        const float* hsrc = h_glob + ((size_t)(l - 1) * 16 + b) * T_ * 128;
        float* rout = ring + ((size_t)li * 16 + b) * (4 * C_ * G_);
        int* fhp = flag_h + (l - 1) * 16 + b;   // upstream rec progress (data)
        int* fhme = flag_h + l * 16 + b;        // our rec progress (backpressure)
        int* fgo = flag_g + li * 16 + b;

        for (int k = 0; k < NCHUNK_; k++) {
            if (tid == 0) {
                wait_ge_(fhp, k + 1);
                if (k >= 4) wait_ge_(fhme, k - 3);
            }
            __syncthreads();   // wait done + previous chunk's hch reads complete
            {   // stage C_*128 = 2048 h values (4 per thread) into padded layout
#pragma unroll
                for (int i = 0; i < 4; i++) {
                    int idx = i * 512 + tid;
                    hch[idx >> 7][HOFF(idx & 127)] =
                        __hip_atomic_load(hsrc + (size_t)k * C_ * 128 + idx,
                                          __ATOMIC_RELAXED, __HIP_MEMORY_SCOPE_AGENT);
                }
            }
            __syncthreads();
#pragma unroll
            for (int s = 0; s < C_; s++) {
                const float* hb = hch[s] + q * 36;
                float z0, z1, z2, z3;
                DOT32(z0, w0, hb);
                DOT32(z1, w1, hb);
                DOT32(z2, w2, hb);
                DOT32(z3, w3, hb);
                z0 += __shfl_xor(z0, 1); z0 += __shfl_xor(z0, 2);
                z1 += __shfl_xor(z1, 1); z1 += __shfl_xor(z1, 2);
                z2 += __shfl_xor(z2, 1); z2 += __shfl_xor(z2, 2);
                z3 += __shfl_xor(z3, 1); z3 += __shfl_xor(z3, 2);
                if (q == 0) {
                    float* ro = rout + ((size_t)(k & 3) * C_ + s) * G_;
                    __hip_atomic_store(ro + r, z0 + bs0, __ATOMIC_RELAXED, __HIP_MEMORY_SCOPE_AGENT);
                    __hip_atomic_store(ro + 128 + r, z1 + bs1, __ATOMIC_RELAXED, __HIP_MEMORY_SCOPE_AGENT);
                    __hip_atomic_store(ro + 256 + r, z2 + bs2, __ATOMIC_RELAXED, __HIP_MEMORY_SCOPE_AGENT);
                    __hip_atomic_store(ro + 384 + r, z3 + bs3, __ATOMIC_RELAXED, __HIP_MEMORY_SCOPE_AGENT);
                }
            }
            __syncthreads();   // drains vmcnt: ring chunk in L2 before publish
            if (tid == 0) __hip_atomic_store(fgo, k + 1, __ATOMIC_RELEASE, __HIP_MEMORY_SCOPE_AGENT);
        }
    }
}

// ---------------- InstanceNorm stats ----------------
__global__ __launch_bounds__(512) void in_stats(const float* __restrict__ in,
                                                float* __restrict__ mu,
                                                float* __restrict__ inv) {
    int b = blockIdx.x;
    int tid = threadIdx.x;
    int h = tid & 127, r = tid >> 7;
    const float* ib = in + (size_t)b * T_ * H_;
    float s = 0.f, q = 0.f;
    for (int t = r; t < T_; t += 4) { float v = ib[t * H_ + h]; s += v; q += v * v; }
    __shared__ float ls[512], lq[512];
    ls[tid] = s; lq[tid] = q;
    __syncthreads();
    if (r == 0) {
        s = ls[h] + ls[h + 128] + ls[h + 256] + ls[h + 384];
        q = lq[h] + lq[h + 128] + lq[h + 256] + lq[h + 384];
        float m = s * (1.f / T_);
        float v = q * (1.f / T_) - m * m;
        mu[b * 128 + h] = m;
        inv[b * 128 + h] = rsqrtf(fmaxf(v, 0.f) + EPS_);
    }
}

__global__ __launch_bounds__(256) void apply_in(const float* __restrict__ in,
                                                const float* __restrict__ mu,
                                                const float* __restrict__ inv,
                                                float* __restrict__ out) {
    int idx = blockIdx.x * 256 + threadIdx.x;
    int h = idx & 127;
    int b = idx >> 15;
    out[idx] = (in[idx] - mu[b * 128 + h]) * inv[b * 128 + h];
}

// ---------------- attention score ----------------
__global__ __launch_bounds__(128) void score_kernel(const float* __restrict__ ph,
                                                    const float* __restrict__ px,
                                                    const float* __restrict__ mu_px,
                                                    const float* __restrict__ inv_px,
                                                    const float* __restrict__ attn_w,
                                                    float* __restrict__ lsc) {
    int bt = blockIdx.x;
    int b = bt >> 8;
    int h = threadIdx.x;
    size_t o = (size_t)bt * 128 + h;
    float v = ph[o] + (px[o] - mu_px[b * 128 + h]) * inv_px[b * 128 + h];
    float sv = tanh_(v) * attn_w[h];
    __shared__ float red[128];
    red[h] = sv;
    __syncthreads();
    for (int off = 64; off > 0; off >>= 1) {
        if (h < off) red[h] += red[h + off];
        __syncthreads();
    }
    if (h == 0) lsc[bt] = red[0];
}

__global__ __launch_bounds__(256) void softmax_t(const float* __restrict__ lsc,
                                                 float* __restrict__ wsm) {
    int b = blockIdx.x;
    int t = threadIdx.x;
    float v = lsc[b * 256 + t];
    __shared__ float red[256];
    red[t] = v; __syncthreads();
    for (int off = 128; off > 0; off >>= 1) { if (t < off) red[t] = fmaxf(red[t], red[t + off]); __syncthreads(); }
    float mx = red[0]; __syncthreads();
    float e = __expf(v - mx);
    red[t] = e; __syncthreads();
    for (int off = 128; off > 0; off >>= 1) { if (t < off) red[t] += red[t + off]; __syncthreads(); }
    wsm[b * 256 + t] = e / red[0];
}

__global__ __launch_bounds__(256) void att_map_write(const float* __restrict__ wsm,
                                                     float* __restrict__ out_att) {
    int idx = blockIdx.x * 256 + threadIdx.x;   // B*T*D
    int b = idx >> 15;
    int t = (idx >> 7) & 255;
    out_att[idx] = wsm[b * 256 + t] * (1.f / (float)D_);
}

__global__ __launch_bounds__(128) void final_kernel(const float* __restrict__ ph,
                                                    const float* __restrict__ wsm,
                                                    const float* __restrict__ fc_w,
                                                    const float* __restrict__ fc_b,
                                                    float* __restrict__ out) {
    int b = blockIdx.x;
    int h = threadIdx.x;
    const float* pb = ph + (size_t)b * T_ * H_;
    const float* wb = wsm + b * 256;
    float acc = 0.f;
    for (int t = 0; t < T_; t++) acc = fmaf(pb[t * H_ + h], wb[t], acc);
    __shared__ float ctx[128];
    ctx[h] = acc;
    __syncthreads();
    if (h < NC_) {
        float s = fc_b[h];
        const float* fw = fc_w + h * 128;
        for (int k = 0; k < 128; k++) s = fmaf(ctx[k], fw[k], s);
        out[b * NC_ + h] = s;
    }
}

// ---------------- launcher ----------------
extern "C" void kernel_launch(void* const* d_in, const int* in_sizes, int n_in,
                              void* d_out, int out_size, void* d_ws, size_t ws_size,
                              hipStream_t stream) {
    const float* x        = (const float*)d_in[0];
    const float* Wih      = (const float*)d_in[1];
    const float* Whh      = (const float*)d_in[2];
    const float* bih      = (const float*)d_in[3];
    const float* bhh      = (const float*)d_in[4];
    const float* proj_h_w = (const float*)d_in[5];
    const float* proj_h_b = (const float*)d_in[6];
    const float* proj_x_w = (const float*)d_in[7];
    const float* proj_x_b = (const float*)d_in[8];
    const float* attn_w   = (const float*)d_in[9];
    const float* fc_w     = (const float*)d_in[10];
    const float* fc_b     = (const float*)d_in[11];
    float* out = (float*)d_out;

    float* ws = (float*)d_ws;
    const size_t NTD = (size_t)B_ * T_ * D_;       // 524288
    float* xnorm  = ws;                            // NTD
    float* h_glob = xnorm + NTD;                   // 4*NTD
    float* g0     = h_glob + 4 * NTD;              // B*T*G = 4*NTD
    float* ring   = g0 + 4 * NTD;                  // 3*16*4*C_*G
    float* smalls = ring + (size_t)3 * 16 * 4 * C_ * G_;
    float* sum_bd = smalls;
    float* sq_bd  = sum_bd + 2048;
    float* sdv    = sq_bd + 2048;
    float* mu_ln  = sdv + 128;
    float* inv_ln = mu_ln + 2048;
    float* mu_px  = inv_ln + 2048;
    float* inv_px = mu_px + 2048;
    float* lsc    = inv_px + 2048;
    float* wsm    = lsc + 4096;
    int*   flags  = (int*)(wsm + 4096);
    int*   flag_h = flags;                         // [64]
    int*   flag_g = flags + 64;                    // [48]
    // post-scan reuse (dispatch-boundary ordering):
    float* lnorm = g0;                             // g0 dead after scan
    float* ph    = h_glob;                         // layer-0/1 h dead after scan
    float* px    = h_glob + NTD;
    const float* h3 = h_glob + 3 * NTD;

    hipMemsetAsync((void*)flags, 0, 128 * sizeof(int), stream);

    // input normalize
    stats_bd<<<16, 512, 0, stream>>>(x, sum_bd, sq_bd);
    stats_d<<<1, 128, 0, stream>>>(sum_bd, sq_bd, sdv);
    normalize_x<<<2048, 256, 0, stream>>>(x, sum_bd, sq_bd, sdv, xnorm);

    // layer-0 input projection (time-parallel GEMM), then chunk-pipelined stack
    dim3 g1(64, 8);
    gemm_bias_k128<<<g1, 256, 0, stream>>>(xnorm, Wih, bih, bhh, g0, G_);
    scan_pipe4<<<112, 512, 0, stream>>>(g0, Wih, Whh, bih, bhh,
                                        h_glob, ring, flag_h, flag_g);

    // post-LSTM instancenorm + projections
    in_stats<<<16, 512, 0, stream>>>(h3, mu_ln, inv_ln);
    apply_in<<<2048, 256, 0, stream>>>(h3, mu_ln, inv_ln, lnorm);
    dim3 g2(64, 2);
    gemm_bias_k128<<<g2, 256, 0, stream>>>(lnorm, proj_h_w, proj_h_b, nullptr, ph, H_);
    gemm_bias_k128<<<g2, 256, 0, stream>>>(xnorm, proj_x_w, proj_x_b, nullptr, px, H_);
    in_stats<<<16, 512, 0, stream>>>(px, mu_px, inv_px);

    // attention + classify
    score_kernel<<<4096, 128, 0, stream>>>(ph, px, mu_px, inv_px, attn_w, lsc);
    softmax_t<<<16, 256, 0, stream>>>(lsc, wsm);
    att_map_write<<<2048, 256, 0, stream>>>(wsm, out + B_ * NC_);
    final_kernel<<<16, 128, 0, stream>>>(ph, wsm, fc_w, fc_b, out);
}